// Round 1
// baseline (2209.369 us; speedup 1.0000x reference)
//
#include <hip/hip_runtime.h>
#include <math.h>

#define NT 512

constexpr int K  = 1024;
constexpr int TI = 64;
constexpr int TJ = 64;
constexpr float BN_EPS = 1e-3f;

// One fused GCN block:  y = (T @ x) / rowsum(T);  z = concat(y, x_i) @ W + b;
// then (non-final) BN + concat(z, relu(z)) -> out rows, or (final) partial
// column-sums of z -> part buffer.
// T is regenerated on the fly from coordinates (never materialized in HBM).
template<int FIN, bool FINAL>
__global__ __launch_bounds__(NT)
void block_kernel(const float* __restrict__ xin,     // [B,K,FIN]
                  const float* __restrict__ coords,  // [B,K,3]
                  const float* __restrict__ psq,     // [1]
                  const float* __restrict__ W,       // [2*FIN, H]
                  const float* __restrict__ bias,    // [1]
                  const float* __restrict__ gamma,   // [64] or null
                  const float* __restrict__ beta,    // [64] or null
                  float* __restrict__ out)           // [B,K,128] or part [B,16,4]
{
    constexpr int H    = FINAL ? 4 : 64;
    constexpr int FTOT = 2 * FIN;

    const int it  = blockIdx.x;   // 0..15  (i tile)
    const int b   = blockIdx.y;   // 0..31  (sample)
    const int t   = threadIdx.x;
    const int i0g = it * TI;

    __shared__ __align__(16) float4 sC4[K];             // coords+norm, whole sample
    __shared__ __align__(16) float  sT[TJ][TI];         // t-tile transposed [jj][ii]
    __shared__ __align__(16) float  sX[TJ][FIN];        // x_j tile
    __shared__ __align__(16) float  sYt[FIN][TI + 2];   // normalized y, [f][i]
    __shared__ __align__(16) float  sXiT[FIN][TI + 2];  // x_i tile, [f][i]
    __shared__ __align__(16) float  sW[64 * H];         // dense weight chunk
    __shared__ float  sRedR[8][TI];
    __shared__ float  sRinv[TI];
    __shared__ float  sRed[4][TI];
    __shared__ __align__(16) float sOutSmall[(FIN == 16 && !FINAL) ? TI * 128 : 4];

    const float p = psq[0];

    // ---- stage coords(+norms) for whole sample, and x_i tile (transposed) ----
    for (int k = t; k < K; k += NT) {
        const float* c = coords + (size_t)(b * K + k) * 3;
        float cx = c[0], cy = c[1], cz = c[2];
        sC4[k] = make_float4(cx, cy, cz, cx * cx + cy * cy + cz * cz);
    }
    for (int idx = t; idx < TI * FIN; idx += NT) {
        int i = idx / FIN, f = idx % FIN;
        sXiT[f][i] = xin[(size_t)(b * K + i0g + i) * FIN + f];
    }
    __syncthreads();

    // gen role: row gii, j-group gjg
    const int gii = t & 63;
    const int gjg = t >> 6;      // 0..7
    const float4 ci = sC4[i0g + gii];
    float rsum = 0.f;

    float acc[4][4];
#pragma unroll
    for (int r = 0; r < 4; ++r)
#pragma unroll
        for (int q = 0; q < 4; ++q) acc[r][q] = 0.f;

    for (int jt = 0; jt < K / TJ; ++jt) {
        const int j0 = jt * TJ;
        __syncthreads();   // previous iteration's readers done with sX/sT
        // stage x_j tile (flat contiguous copy)
        {
            const float4* src = (const float4*)(xin + (size_t)(b * K + j0) * FIN);
            float4* dst = (float4*)&sX[0][0];
            for (int v = t; v < TJ * FIN / 4; v += NT) dst[v] = src[v];
        }
        // generate T tile (transposed)
#pragma unroll
        for (int q = 0; q < 8; ++q) {
            const int jj = gjg * 8 + q;
            const float4 cj = sC4[j0 + jj];
            float d  = ci.w + cj.w - 2.f * (ci.x * cj.x + ci.y * cj.y + ci.z * cj.z);
            float tv = __expf(__expf(-d * p));
            sT[jj][gii] = tv;
            rsum += tv;
        }
        __syncthreads();
        // y[i][f] += sT[jj][i] * sX[jj][f]
        if constexpr (FIN == 128) {
            const int f0 = (t & 31) * 4;
            const int i0 = (t >> 5) * 4;
#pragma unroll 4
            for (int jj = 0; jj < TJ; ++jj) {
                const float4 tv = *(const float4*)&sT[jj][i0];
                const float4 xv = *(const float4*)&sX[jj][f0];
                acc[0][0] += tv.x * xv.x; acc[0][1] += tv.x * xv.y; acc[0][2] += tv.x * xv.z; acc[0][3] += tv.x * xv.w;
                acc[1][0] += tv.y * xv.x; acc[1][1] += tv.y * xv.y; acc[1][2] += tv.y * xv.z; acc[1][3] += tv.y * xv.w;
                acc[2][0] += tv.z * xv.x; acc[2][1] += tv.z * xv.y; acc[2][2] += tv.z * xv.z; acc[2][3] += tv.z * xv.w;
                acc[3][0] += tv.w * xv.x; acc[3][1] += tv.w * xv.y; acc[3][2] += tv.w * xv.z; acc[3][3] += tv.w * xv.w;
            }
        } else {
            const int f0 = (t & 7) * 2;
            const int ii = t >> 3;
#pragma unroll 4
            for (int jj = 0; jj < TJ; ++jj) {
                const float  tv = sT[jj][ii];
                const float2 xv = *(const float2*)&sX[jj][f0];
                acc[0][0] += tv * xv.x;
                acc[0][1] += tv * xv.y;
            }
        }
    }

    // ---- softmax row sums -> 1/R ----
    sRedR[gjg][gii] = rsum;
    __syncthreads();
    if (t < TI) {
        float s = 0.f;
#pragma unroll
        for (int g = 0; g < 8; ++g) s += sRedR[g][t];
        sRinv[t] = 1.f / s;
    }
    __syncthreads();

    // ---- write normalized y to sYt [f][i] ----
    if constexpr (FIN == 128) {
        const int f0 = (t & 31) * 4;
        const int i0 = (t >> 5) * 4;
#pragma unroll
        for (int r = 0; r < 4; ++r) {
            const float rv = sRinv[i0 + r];
#pragma unroll
            for (int q = 0; q < 4; ++q) sYt[f0 + q][i0 + r] = acc[r][q] * rv;
        }
    } else {
        const int f0 = (t & 7) * 2;
        const int ii = t >> 3;
        const float rv = sRinv[ii];
        sYt[f0][ii]     = acc[0][0] * rv;
        sYt[f0 + 1][ii] = acc[0][1] * rv;
    }
    __syncthreads();

    // ---- dense: z[i][h] = sum_f concat(y, x_i)[i][f] * W[f][h] + b ----
    const int di  = t & 63;
    const int dhg = t >> 6;   // 0..7
    float dacc[FINAL ? 1 : 8];
    const float bv = bias[0];
#pragma unroll
    for (int q = 0; q < (FINAL ? 1 : 8); ++q) dacc[q] = bv;

    for (int cf = 0; cf < FTOT; cf += 64) {
        const int rows = (FTOT - cf) < 64 ? (FTOT - cf) : 64;
        __syncthreads();
        {
            const float4* src = (const float4*)(W + (size_t)cf * H);
            float4* dst = (float4*)sW;
            for (int v = t; v < rows * H / 4; v += NT) dst[v] = src[v];
        }
        __syncthreads();
        for (int fl = 0; fl < rows; ++fl) {
            const int f = cf + fl;
            const float v = (f < FIN) ? sYt[f][di] : sXiT[f - FIN][di];
            if constexpr (FINAL) {
                if (dhg < 4) dacc[0] += v * sW[fl * 4 + dhg];
            } else {
                const float* wr = &sW[fl * 64 + dhg * 8];
                const float4 w0 = *(const float4*)wr;
                const float4 w1 = *(const float4*)(wr + 4);
                dacc[0] += v * w0.x; dacc[1] += v * w0.y; dacc[2] += v * w0.z; dacc[3] += v * w0.w;
                dacc[4] += v * w1.x; dacc[5] += v * w1.y; dacc[6] += v * w1.z; dacc[7] += v * w1.w;
            }
        }
    }
    __syncthreads();   // all reads of sYt/sXiT/sW done

    if constexpr (FINAL) {
        if (dhg < 4) sRed[dhg][di] = dacc[0];
        __syncthreads();
        if (t < 4) {
            float s = 0.f;
            for (int i = 0; i < TI; ++i) s += sRed[t][i];
            out[((size_t)b * 16 + it) * 4 + t] = s;
        }
    } else {
        float* stage = (FIN == 16) ? sOutSmall : &sXiT[0][0];
        const float bns = rsqrtf(1.f + BN_EPS);
        float z[8], rz[8];
#pragma unroll
        for (int q = 0; q < 8; ++q) {
            const int h = dhg * 8 + q;
            const float sc = gamma[h] * bns;
            z[q]  = dacc[q] * sc + beta[h];
            rz[q] = fmaxf(z[q], 0.f);
        }
        float* srow = stage + di * 128 + dhg * 8;
        *(float4*)(srow)      = make_float4(z[0],  z[1],  z[2],  z[3]);
        *(float4*)(srow + 4)  = make_float4(z[4],  z[5],  z[6],  z[7]);
        *(float4*)(srow + 64) = make_float4(rz[0], rz[1], rz[2], rz[3]);
        *(float4*)(srow + 68) = make_float4(rz[4], rz[5], rz[6], rz[7]);
        __syncthreads();
        const float4* s4 = (const float4*)stage;
        float4* dstg = (float4*)(out + (size_t)(b * K + i0g) * 128);
        for (int v = t; v < TI * 128 / 4; v += NT) dstg[v] = s4[v];
    }
}

__global__ void finalize_kernel(const float* __restrict__ part, float* __restrict__ out)
{
    const int b = threadIdx.x;
    if (b < 32) {
        float v[4];
#pragma unroll
        for (int h = 0; h < 4; ++h) {
            float s = 0.f;
            for (int i = 0; i < 16; ++i) s += part[(size_t)(b * 16 + i) * 4 + h];
            v[h] = s * (1.f / 1024.f);
        }
        const float m = fmaxf(fmaxf(v[0], v[1]), fmaxf(v[2], v[3]));
        float e[4], se = 0.f;
#pragma unroll
        for (int h = 0; h < 4; ++h) { e[h] = __expf(v[h] - m); se += e[h]; }
        const float inv = 1.f / se;
#pragma unroll
        for (int h = 0; h < 4; ++h) out[b * 4 + h] = e[h] * inv;
    }
}

extern "C" void kernel_launch(void* const* d_in, const int* in_sizes, int n_in,
                              void* d_out, int out_size, void* d_ws, size_t ws_size,
                              hipStream_t stream)
{
    const float* x   = (const float*)d_in[0];
    const float* co  = (const float*)d_in[1];
    const float* psq = (const float*)d_in[2];
    const float* W0  = (const float*)d_in[3];
    const float* W1  = (const float*)d_in[4];
    const float* W2  = (const float*)d_in[5];
    const float* W3  = (const float*)d_in[6];
    const float* b0  = (const float*)d_in[7];
    const float* b1  = (const float*)d_in[8];
    const float* b2  = (const float*)d_in[9];
    const float* b3  = (const float*)d_in[10];
    const float* g0  = (const float*)d_in[11];
    const float* be0 = (const float*)d_in[12];
    const float* g1  = (const float*)d_in[13];
    const float* be1 = (const float*)d_in[14];
    const float* g2  = (const float*)d_in[15];
    const float* be2 = (const float*)d_in[16];
    float* out = (float*)d_out;

    float* xb0  = (float*)d_ws;                       // [32,1024,128]
    float* xb1  = xb0 + (size_t)32 * 1024 * 128;      // [32,1024,128]
    float* part = xb1 + (size_t)32 * 1024 * 128;      // [32,16,4]

    dim3 grid(16, 32);
    block_kernel<16,  false><<<grid, NT, 0, stream>>>(x,   co, psq, W0, b0, g0, be0, xb0);
    block_kernel<128, false><<<grid, NT, 0, stream>>>(xb0, co, psq, W1, b1, g1, be1, xb1);
    block_kernel<128, false><<<grid, NT, 0, stream>>>(xb1, co, psq, W2, b2, g2, be2, xb0);
    block_kernel<128, true ><<<grid, NT, 0, stream>>>(xb0, co, psq, W3, b3, nullptr, nullptr, part);
    finalize_kernel<<<1, 64, 0, stream>>>(part, out);
}

// Round 2
// 269.874 us; speedup vs baseline: 8.1867x; 8.1867x over previous
//
#include <hip/hip_runtime.h>
#include <math.h>

typedef __attribute__((ext_vector_type(8)))  __bf16  bf16x8;
typedef __attribute__((ext_vector_type(4)))  float    f32x4;
typedef __attribute__((ext_vector_type(16))) float    f32x16;
typedef __attribute__((ext_vector_type(4)))  unsigned u32x4;
typedef __attribute__((ext_vector_type(2)))  unsigned u32x2;

__device__ __forceinline__ unsigned short f2bf(float f) {
    unsigned u = __builtin_bit_cast(unsigned, f);
    u += 0x7fffu + ((u >> 16) & 1u);
    return (unsigned short)(u >> 16);
}
__device__ __forceinline__ float bf2f(unsigned short b) {
    unsigned u = ((unsigned)b) << 16;
    return __builtin_bit_cast(float, u);
}
__device__ __forceinline__ unsigned swz3(int key) { return (unsigned)((key ^ (key >> 3)) & 7); }
__device__ __forceinline__ bf16x8 ldfrag(const char* p) { return __builtin_bit_cast(bf16x8, *(const u32x4*)p); }

// ---------------------------------------------------------------------------
// W transpose + hi/lo bf16 split.  Layout in wt (elements):
// [0] WT0hi[64][32]  [2048] WT0lo
// [4096] WT1hi[64][256] [20480] WT1lo
// [36864] WT2hi [53248] WT2lo
// [69632] WT3hi[64][256] (rows 4..63 zero) [86016] WT3lo
__global__ __launch_bounds__(256)
void wconv(const float* __restrict__ W0, const float* __restrict__ W1,
           const float* __restrict__ W2, const float* __restrict__ W3,
           unsigned short* __restrict__ wt)
{
    int id = blockIdx.x * 256 + threadIdx.x;
    if (id >= 51200) return;
    float v; size_t dst; size_t lod;
    if (id < 2048)       { int h = id >> 5, f = id & 31;              v = W0[f*64 + h]; dst = (size_t)h*32 + f;          lod = 2048;  }
    else if (id < 18432) { int j = id - 2048;  int h = j >> 8, f = j & 255; v = W1[f*64 + h]; dst = 4096  + (size_t)h*256 + f; lod = 16384; }
    else if (id < 34816) { int j = id - 18432; int h = j >> 8, f = j & 255; v = W2[f*64 + h]; dst = 36864 + (size_t)h*256 + f; lod = 16384; }
    else                 { int j = id - 34816; int h = j >> 8, f = j & 255; v = (h < 4) ? W3[f*4 + h] : 0.f; dst = 69632 + (size_t)h*256 + f; lod = 16384; }
    unsigned short hb = f2bf(v);
    unsigned short lb = f2bf(v - bf2f(hb));
    wt[dst] = hb;
    wt[dst + lod] = lb;
}

// x fp32 [32][1024][16] -> xT0 bf16 [32][16][1024] + xR0 bf16 [32][1024][16]
__global__ __launch_bounds__(256)
void x0conv(const float* __restrict__ x, unsigned short* __restrict__ xT0,
            unsigned short* __restrict__ xR0)
{
    int id = blockIdx.x * 256 + threadIdx.x;   // 32768 = 32*1024
    int b = id >> 10, j = id & 1023;
    const float* s = x + (size_t)id * 16;
    unsigned pk[8];
#pragma unroll
    for (int f = 0; f < 16; f += 2) {
        unsigned short h0 = f2bf(s[f]);
        unsigned short h1 = f2bf(s[f + 1]);
        xT0[((size_t)b*16 + f    )*1024 + j] = h0;
        xT0[((size_t)b*16 + f + 1)*1024 + j] = h1;
        pk[f >> 1] = (unsigned)h0 | ((unsigned)h1 << 16);
    }
    u32x4* d = (u32x4*)(xR0 + (size_t)id * 16);
    u32x4 v0 = {pk[0], pk[1], pk[2], pk[3]};
    u32x4 v1 = {pk[4], pk[5], pk[6], pk[7]};
    d[0] = v0; d[1] = v1;
}

// ---------------------------------------------------------------------------
// One fused GCN block. MODE 0: F=16 (first), 1: F=128 mid, 2: F=128 final.
// Computes y^T = x^T @ T^T (MFMA, T hi/lo), normalize, z^T = WT @ concat^T
// (MFMA, W hi/lo), then BN+emit next-layer bf16 planes (or partial means).
template<int MODE>
__global__ __launch_bounds__(256, 2)
void gcn_block(const unsigned short* __restrict__ xT, const unsigned short* __restrict__ xR,
               const float* __restrict__ coords, const float* __restrict__ psq,
               const unsigned short* __restrict__ WThi, const unsigned short* __restrict__ WTlo,
               const float* __restrict__ gamma, const float* __restrict__ beta,
               const float* __restrict__ bias,
               unsigned short* __restrict__ oxT, unsigned short* __restrict__ oxR,
               float* __restrict__ part)
{
    __shared__ char smem[65536];
    constexpr int XTO = 0;            // main: x^T tile  (rows of 128B)
    constexpr int THI = 16 * 1024;    // T hi [64][128B] (swizzled)
    constexpr int TLO = 24 * 1024;
    constexpr int SC4 = 32 * 1024;    // coords float4[1024]; later RED/RINV/SPT
    constexpr int YL  = 0;            // dense (MODE1/2): y bf16 [64][256B]
    constexpr int XI  = 16 * 1024;    // dense: xi bf16 [64][256B]
    constexpr int WTB = 32 * 1024;    // dense: WT hi [64][256B] @32K, lo @48K
    constexpr int C0O = 0;            // MODE0 dense: concat [64][64B]
    constexpr int W0H = 4 * 1024;     // MODE0: WT0 hi [64][64B]
    constexpr int W0L = 8 * 1024;
    constexpr int ZT  = 0;            // z fp32 [64][65]
    constexpr int RED = SC4;
    constexpr int RIV = SC4 + 1024;
    constexpr int SPT = SC4;

    const int t = threadIdx.x;
    const int l = t & 63;
    const int w = t >> 6;
    const int b  = blockIdx.y;
    const int it = blockIdx.x;
    const int i0g = it * 64;
    const float p = psq[0];
    float bv = 0.f;
    if constexpr (MODE != 2) bv = bias[0];

    // ---- coords (+ norms) for whole sample ----
    float4* sc = (float4*)(smem + SC4);
    for (int k = t; k < 1024; k += 256) {
        const float* c = coords + ((size_t)b * 1024 + k) * 3;
        float cx = c[0], cy = c[1], cz = c[2];
        sc[k] = make_float4(cx, cy, cz, cx*cx + cy*cy + cz*cz);
    }
    __syncthreads();
    const float4 ci = sc[i0g + l];      // T-gen row (i = l, jg = w)
    float rsum = 0.f;

    const int m31 = l & 31, kg = l >> 5;
    const int m15 = l & 15, kg4 = l >> 4;
    const int wf = w >> 1, wi = w & 1;

    int fA0 = 0, fA1 = 0, iB = 0;
    if constexpr (MODE) { fA0 = wf*64 + m31; fA1 = fA0 + 32; iB = wi*32 + m31; }
    else                { fA0 = m15;                          iB = w*16 + m15; }

    f32x16 acc0, acc1; f32x4 acc4;
#pragma unroll
    for (int r = 0; r < 16; ++r) { acc0[r] = 0.f; acc1[r] = 0.f; }
#pragma unroll
    for (int r = 0; r < 4; ++r) acc4[r] = 0.f;

    // ================= main loop over j-tiles =================
    for (int jt = 0; jt < 16; ++jt) {
        __syncthreads();
        // stage x^T tile (global bf16 -> LDS, row-swizzled)
        if constexpr (MODE) {
            const int f = t >> 1, hf = t & 1;
            const unsigned short* g = xT + ((size_t)b*128 + f)*1024 + jt*64 + hf*32;
            u32x4 v0 = *(const u32x4*)(g);
            u32x4 v1 = *(const u32x4*)(g + 8);
            u32x4 v2 = *(const u32x4*)(g + 16);
            u32x4 v3 = *(const u32x4*)(g + 24);
            char* row = smem + XTO + f*128;
            const unsigned sw = swz3(f) << 4;
            *(u32x4*)(row + ((hf*64 +  0) ^ sw)) = v0;
            *(u32x4*)(row + ((hf*64 + 16) ^ sw)) = v1;
            *(u32x4*)(row + ((hf*64 + 32) ^ sw)) = v2;
            *(u32x4*)(row + ((hf*64 + 48) ^ sw)) = v3;
        } else {
            if (t < 128) {
                const int f = t >> 3, g8 = t & 7;
                const unsigned short* g = xT + ((size_t)b*16 + f)*1024 + jt*64 + g8*8;
                u32x4 v = *(const u32x4*)g;
                *(u32x4*)(smem + XTO + f*128 + ((g8*16) ^ (swz3(f) << 4))) = v;
            }
        }
        // T generation: thread (i=l, jg=w) does 16 consecutive j
        {
            const int j0 = jt*64 + w*16;
            float tvv[16];
#pragma unroll
            for (int q = 0; q < 16; ++q) {
                float4 cj = sc[j0 + q];
                float d = ci.w + cj.w - 2.f*(ci.x*cj.x + ci.y*cj.y + ci.z*cj.z);
                tvv[q] = __expf(__expf(-d * p));
                rsum += tvv[q];
            }
            unsigned hp[8], lp[8];
#pragma unroll
            for (int q = 0; q < 8; ++q) {
                unsigned short h0 = f2bf(tvv[2*q]), h1 = f2bf(tvv[2*q+1]);
                unsigned short l0 = f2bf(tvv[2*q] - bf2f(h0));
                unsigned short l1 = f2bf(tvv[2*q+1] - bf2f(h1));
                hp[q] = (unsigned)h0 | ((unsigned)h1 << 16);
                lp[q] = (unsigned)l0 | ((unsigned)l1 << 16);
            }
            const unsigned sw = swz3(l) << 4;
            char* th = smem + THI + l*128;
            char* tl = smem + TLO + l*128;
            u32x4 a = {hp[0], hp[1], hp[2], hp[3]}, c = {hp[4], hp[5], hp[6], hp[7]};
            u32x4 e = {lp[0], lp[1], lp[2], lp[3]}, f = {lp[4], lp[5], lp[6], lp[7]};
            *(u32x4*)(th + ((w*32 +  0) ^ sw)) = a;
            *(u32x4*)(th + ((w*32 + 16) ^ sw)) = c;
            *(u32x4*)(tl + ((w*32 +  0) ^ sw)) = e;
            *(u32x4*)(tl + ((w*32 + 16) ^ sw)) = f;
        }
        __syncthreads();
        // MFMA: y^T += x^T (hi) * T^T (hi+lo)
        if constexpr (MODE) {
            const char* rA0 = smem + XTO + fA0*128; const unsigned sA0 = swz3(fA0) << 4;
            const char* rA1 = smem + XTO + fA1*128; const unsigned sA1 = swz3(fA1) << 4;
            const char* rBh = smem + THI + iB*128;  const unsigned sB  = swz3(iB) << 4;
            const char* rBl = smem + TLO + iB*128;
#pragma unroll
            for (int kk = 0; kk < 4; ++kk) {
                const unsigned off = kk*32 + kg*16;
                bf16x8 a0 = ldfrag(rA0 + (off ^ sA0));
                bf16x8 a1 = ldfrag(rA1 + (off ^ sA1));
                bf16x8 bh = ldfrag(rBh + (off ^ sB));
                bf16x8 bl = ldfrag(rBl + (off ^ sB));
                acc0 = __builtin_amdgcn_mfma_f32_32x32x16_bf16(a0, bh, acc0, 0, 0, 0);
                acc1 = __builtin_amdgcn_mfma_f32_32x32x16_bf16(a1, bh, acc1, 0, 0, 0);
                acc0 = __builtin_amdgcn_mfma_f32_32x32x16_bf16(a0, bl, acc0, 0, 0, 0);
                acc1 = __builtin_amdgcn_mfma_f32_32x32x16_bf16(a1, bl, acc1, 0, 0, 0);
            }
        } else {
            const char* rA  = smem + XTO + fA0*128; const unsigned sA = swz3(fA0) << 4;
            const char* rBh = smem + THI + iB*128;  const unsigned sB = swz3(iB) << 4;
            const char* rBl = smem + TLO + iB*128;
#pragma unroll
            for (int kk = 0; kk < 2; ++kk) {
                const unsigned off = kk*64 + kg4*16;
                bf16x8 a  = ldfrag(rA  + (off ^ sA));
                bf16x8 bh = ldfrag(rBh + (off ^ sB));
                bf16x8 bl = ldfrag(rBl + (off ^ sB));
                acc4 = __builtin_amdgcn_mfma_f32_16x16x32_bf16(a, bh, acc4, 0, 0, 0);
                acc4 = __builtin_amdgcn_mfma_f32_16x16x32_bf16(a, bl, acc4, 0, 0, 0);
            }
        }
    }

    // ---- softmax row sums ----
    __syncthreads();
    ((float*)(smem + RED))[w*64 + l] = rsum;
    __syncthreads();
    if (t < 64) {
        const float* rr = (const float*)(smem + RED);
        float s = rr[t] + rr[64 + t] + rr[128 + t] + rr[192 + t];
        ((float*)(smem + RIV))[t] = 1.f / s;
    }
    __syncthreads();

    // ---- normalize y, write bf16 into dense concat buffers; stage xi ----
    if constexpr (MODE) {
        const float rv = ((const float*)(smem + RIV))[iB];
        acc0 *= rv; acc1 *= rv;
        char* yrow = smem + YL + iB*256;
        const unsigned swi = swz3(iB) << 4;
#pragma unroll
        for (int rq = 0; rq < 4; ++rq) {
            unsigned q0 = (unsigned)f2bf(acc0[rq*4+0]) | ((unsigned)f2bf(acc0[rq*4+1]) << 16);
            unsigned q1 = (unsigned)f2bf(acc0[rq*4+2]) | ((unsigned)f2bf(acc0[rq*4+3]) << 16);
            u32x2 w0 = {q0, q1};
            *(u32x2*)(yrow + ((wf*128 + rq*16 + kg*8) ^ swi)) = w0;
            unsigned r0 = (unsigned)f2bf(acc1[rq*4+0]) | ((unsigned)f2bf(acc1[rq*4+1]) << 16);
            unsigned r1 = (unsigned)f2bf(acc1[rq*4+2]) | ((unsigned)f2bf(acc1[rq*4+3]) << 16);
            u32x2 w1 = {r0, r1};
            *(u32x2*)(yrow + ((wf*128 + 64 + rq*16 + kg*8) ^ swi)) = w1;
        }
        // xi tile [64][128] bf16 from xR plane
        const int xi_i = t >> 2, xq = t & 3;
        const unsigned short* gx = xR + ((size_t)(b*1024 + i0g + xi_i))*128 + xq*32;
        char* xrow = smem + XI + xi_i*256;
        const unsigned swx = swz3(xi_i) << 4;
#pragma unroll
        for (int g = 0; g < 4; ++g) {
            u32x4 v = *(const u32x4*)(gx + g*8);
            *(u32x4*)(xrow + ((xq*64 + g*16) ^ swx)) = v;
        }
    } else {
        const float rv = ((const float*)(smem + RIV))[iB];
        acc4 *= rv;
        unsigned q0 = (unsigned)f2bf(acc4[0]) | ((unsigned)f2bf(acc4[1]) << 16);
        unsigned q1 = (unsigned)f2bf(acc4[2]) | ((unsigned)f2bf(acc4[3]) << 16);
        u32x2 w0 = {q0, q1};
        *(u32x2*)(smem + C0O + iB*64 + ((kg4*8) ^ ((swz3(iB) & 3) << 4))) = w0;
        const int xi_i = t >> 2, xq = t & 3;
        const unsigned short* gx = xR + ((size_t)(b*1024 + i0g + xi_i))*16 + xq*4;
        u32x2 v = *(const u32x2*)gx;
        *(u32x2*)(smem + C0O + xi_i*64 + ((32 + xq*8) ^ ((swz3(xi_i) & 3) << 4))) = v;
    }
    __syncthreads();

    // ---- dense: z^T = WT (hi+lo) @ concat^T ----
    f32x16 dacc; f32x4 da0, da1, da2, da3;
#pragma unroll
    for (int r = 0; r < 16; ++r) dacc[r] = bv;
#pragma unroll
    for (int r = 0; r < 4; ++r) { da0[r] = bv; da1[r] = bv; da2[r] = bv; da3[r] = bv; }

    if constexpr (MODE) {
        // stage WT part A (f 0..127) for hi and lo planes
        {
            const int pl = t >> 7, h = (t >> 1) & 63, hf = t & 1;
            const unsigned short* gw = (pl ? WTlo : WThi) + h*256 + hf*64;
            char* wrow = smem + WTB + pl*16384 + h*256;
            const unsigned sw = swz3(h) << 4;
#pragma unroll
            for (int g = 0; g < 8; ++g) {
                u32x4 v = *(const u32x4*)(gw + g*8);
                *(u32x4*)(wrow + ((hf*128 + g*16) ^ sw)) = v;
            }
        }
        __syncthreads();
        const int hA = wf*32 + m31;
        const char* rWh = smem + WTB + hA*256;         const unsigned sH = swz3(hA) << 4;
        const char* rWl = smem + WTB + 16384 + hA*256;
        const char* rBY = smem + YL + iB*256;          const unsigned sI = swz3(iB) << 4;
#pragma unroll
        for (int k8 = 0; k8 < 8; ++k8) {
            const unsigned off = k8*32 + kg*16;
            bf16x8 ah = ldfrag(rWh + (off ^ sH));
            bf16x8 al = ldfrag(rWl + (off ^ sH));
            bf16x8 bb = ldfrag(rBY + (off ^ sI));
            dacc = __builtin_amdgcn_mfma_f32_32x32x16_bf16(ah, bb, dacc, 0, 0, 0);
            dacc = __builtin_amdgcn_mfma_f32_32x32x16_bf16(al, bb, dacc, 0, 0, 0);
        }
        __syncthreads();
        // stage WT part B (f 128..255)
        {
            const int pl = t >> 7, h = (t >> 1) & 63, hf = t & 1;
            const unsigned short* gw = (pl ? WTlo : WThi) + h*256 + 128 + hf*64;
            char* wrow = smem + WTB + pl*16384 + h*256;
            const unsigned sw = swz3(h) << 4;
#pragma unroll
            for (int g = 0; g < 8; ++g) {
                u32x4 v = *(const u32x4*)(gw + g*8);
                *(u32x4*)(wrow + ((hf*128 + g*16) ^ sw)) = v;
            }
        }
        __syncthreads();
        const char* rBX = smem + XI + iB*256;
#pragma unroll
        for (int k8 = 0; k8 < 8; ++k8) {
            const unsigned off = k8*32 + kg*16;
            bf16x8 ah = ldfrag(rWh + (off ^ sH));
            bf16x8 al = ldfrag(rWl + (off ^ sH));
            bf16x8 bb = ldfrag(rBX + (off ^ sI));
            dacc = __builtin_amdgcn_mfma_f32_32x32x16_bf16(ah, bb, dacc, 0, 0, 0);
            dacc = __builtin_amdgcn_mfma_f32_32x32x16_bf16(al, bb, dacc, 0, 0, 0);
        }
        __syncthreads();
    } else {
        // MODE0: stage WT0 (both planes), single K=32 contraction
        {
            const int pl = t >> 7, h = (t & 127) >> 1, hf = t & 1;
            const unsigned short* gw = (pl ? WTlo : WThi) + h*32 + hf*16;
            char* wrow = smem + (pl ? W0L : W0H) + h*64;
            const unsigned sw2 = (swz3(h) & 3) << 4;
#pragma unroll
            for (int g = 0; g < 2; ++g) {
                u32x4 v = *(const u32x4*)(gw + g*8);
                *(u32x4*)(wrow + (((hf*2 + g)*16) ^ sw2)) = v;
            }
        }
        __syncthreads();
        const int hA = w*16 + m15;
        const unsigned sH2 = (swz3(hA) & 3) << 4;
        bf16x8 ah = ldfrag(smem + W0H + hA*64 + ((kg4*16) ^ sH2));
        bf16x8 al = ldfrag(smem + W0L + hA*64 + ((kg4*16) ^ sH2));
        {
            const int i0 = m15;
            bf16x8 b0 = ldfrag(smem + C0O + (i0     )*64 + ((kg4*16) ^ ((swz3(i0     ) & 3) << 4)));
            bf16x8 b1 = ldfrag(smem + C0O + (i0 + 16)*64 + ((kg4*16) ^ ((swz3(i0 + 16) & 3) << 4)));
            bf16x8 b2 = ldfrag(smem + C0O + (i0 + 32)*64 + ((kg4*16) ^ ((swz3(i0 + 32) & 3) << 4)));
            bf16x8 b3 = ldfrag(smem + C0O + (i0 + 48)*64 + ((kg4*16) ^ ((swz3(i0 + 48) & 3) << 4)));
            da0 = __builtin_amdgcn_mfma_f32_16x16x32_bf16(ah, b0, da0, 0, 0, 0);
            da0 = __builtin_amdgcn_mfma_f32_16x16x32_bf16(al, b0, da0, 0, 0, 0);
            da1 = __builtin_amdgcn_mfma_f32_16x16x32_bf16(ah, b1, da1, 0, 0, 0);
            da1 = __builtin_amdgcn_mfma_f32_16x16x32_bf16(al, b1, da1, 0, 0, 0);
            da2 = __builtin_amdgcn_mfma_f32_16x16x32_bf16(ah, b2, da2, 0, 0, 0);
            da2 = __builtin_amdgcn_mfma_f32_16x16x32_bf16(al, b2, da2, 0, 0, 0);
            da3 = __builtin_amdgcn_mfma_f32_16x16x32_bf16(ah, b3, da3, 0, 0, 0);
            da3 = __builtin_amdgcn_mfma_f32_16x16x32_bf16(al, b3, da3, 0, 0, 0);
        }
        __syncthreads();
    }

    // ---- epilogue ----
    float* zt = (float*)(smem + ZT);
    if constexpr (MODE == 2) {
        // partial column means: h = 0..3 live in waves with wf==0, lanes<32, regs 0..3
        if (wf == 0) {
#pragma unroll
            for (int r = 0; r < 4; ++r) {
                float v = dacc[r];
                v += __shfl_xor(v, 1);  v += __shfl_xor(v, 2);  v += __shfl_xor(v, 4);
                v += __shfl_xor(v, 8);  v += __shfl_xor(v, 16);
                if (l == 0) ((float*)(smem + SPT))[w*4 + r] = v;
            }
        }
        __syncthreads();
        if (t < 4) {
            const float* sp = (const float*)(smem + SPT);
            part[((size_t)b*16 + it)*4 + t] = sp[t] + sp[4 + t];
        }
        return;
    } else {
        const float bns = rsqrtf(1.f + 1e-3f);
        if constexpr (MODE) {
#pragma unroll
            for (int r = 0; r < 16; ++r) {
                const int h = wf*32 + (r & 3) + 8*(r >> 2) + 4*kg;
                float zz = dacc[r];
                zz = zz * (gamma[h] * bns) + beta[h];
                zt[h*65 + iB] = zz;
            }
        } else {
#pragma unroll
            for (int r = 0; r < 4; ++r) {
                const int h = w*16 + kg4*4 + r;
                const float gs = gamma[h] * bns, bt = beta[h];
                zt[h*65 + (m15     )] = da0[r] * gs + bt;
                zt[h*65 + (m15 + 16)] = da1[r] * gs + bt;
                zt[h*65 + (m15 + 32)] = da2[r] * gs + bt;
                zt[h*65 + (m15 + 48)] = da3[r] * gs + bt;
            }
        }
        __syncthreads();
        // emit next-layer planes: xT' [128][1024], xR' [1024][128]
        {
            const int h = t & 63, ic = (t >> 6) * 16;
            const float* zr = zt + h*65 + ic;
            unsigned pz[8], pr[8];
#pragma unroll
            for (int q = 0; q < 8; ++q) {
                float z0 = zr[2*q], z1 = zr[2*q + 1];
                pz[q] = (unsigned)f2bf(z0) | ((unsigned)f2bf(z1) << 16);
                pr[q] = (unsigned)f2bf(fmaxf(z0, 0.f)) | ((unsigned)f2bf(fmaxf(z1, 0.f)) << 16);
            }
            unsigned short* d0 = oxT + ((size_t)b*128 + h     )*1024 + i0g + ic;
            unsigned short* d1 = oxT + ((size_t)b*128 + h + 64)*1024 + i0g + ic;
            u32x4 a = {pz[0], pz[1], pz[2], pz[3]}, c = {pz[4], pz[5], pz[6], pz[7]};
            u32x4 e = {pr[0], pr[1], pr[2], pr[3]}, f = {pr[4], pr[5], pr[6], pr[7]};
            *(u32x4*)(d0) = a; *(u32x4*)(d0 + 8) = c;
            *(u32x4*)(d1) = e; *(u32x4*)(d1 + 8) = f;
        }
        {
            const int i = t >> 2, fq = t & 3;
            unsigned pk[16];
#pragma unroll
            for (int ff = 0; ff < 16; ++ff) {
                const int f0 = fq*32 + ff*2, f1 = f0 + 1;
                float v0 = (f0 < 64) ? zt[f0*65 + i] : fmaxf(zt[(f0 - 64)*65 + i], 0.f);
                float v1 = (f1 < 64) ? zt[f1*65 + i] : fmaxf(zt[(f1 - 64)*65 + i], 0.f);
                pk[ff] = (unsigned)f2bf(v0) | ((unsigned)f2bf(v1) << 16);
            }
            unsigned short* d = oxR + ((size_t)(b*1024 + i0g + i))*128 + fq*32;
            u32x4 a = {pk[0],  pk[1],  pk[2],  pk[3]};
            u32x4 c = {pk[4],  pk[5],  pk[6],  pk[7]};
            u32x4 e = {pk[8],  pk[9],  pk[10], pk[11]};
            u32x4 f = {pk[12], pk[13], pk[14], pk[15]};
            *(u32x4*)(d)      = a; *(u32x4*)(d + 8)  = c;
            *(u32x4*)(d + 16) = e; *(u32x4*)(d + 24) = f;
        }
    }
}

__global__ void finalize_kernel(const float* __restrict__ part, const float* __restrict__ b3,
                                float* __restrict__ out)
{
    const int b = threadIdx.x;
    if (b < 32) {
        float v[4] = {0.f, 0.f, 0.f, 0.f};
        for (int i = 0; i < 16; ++i)
#pragma unroll
            for (int h = 0; h < 4; ++h) v[h] += part[((size_t)b*16 + i)*4 + h];
        const float bb = b3[0];
#pragma unroll
        for (int h = 0; h < 4; ++h) v[h] = v[h] * (1.f / 1024.f) + bb;
        const float m = fmaxf(fmaxf(v[0], v[1]), fmaxf(v[2], v[3]));
        float e[4], se = 0.f;
#pragma unroll
        for (int h = 0; h < 4; ++h) { e[h] = __expf(v[h] - m); se += e[h]; }
        const float inv = 1.f / se;
#pragma unroll
        for (int h = 0; h < 4; ++h) out[b*4 + h] = e[h] * inv;
    }
}

extern "C" void kernel_launch(void* const* d_in, const int* in_sizes, int n_in,
                              void* d_out, int out_size, void* d_ws, size_t ws_size,
                              hipStream_t stream)
{
    const float* x   = (const float*)d_in[0];
    const float* co  = (const float*)d_in[1];
    const float* psq = (const float*)d_in[2];
    const float* W0  = (const float*)d_in[3];
    const float* W1  = (const float*)d_in[4];
    const float* W2  = (const float*)d_in[5];
    const float* W3  = (const float*)d_in[6];
    const float* b0  = (const float*)d_in[7];
    const float* b1  = (const float*)d_in[8];
    const float* b2  = (const float*)d_in[9];
    const float* b3  = (const float*)d_in[10];
    const float* g0  = (const float*)d_in[11];
    const float* be0 = (const float*)d_in[12];
    const float* g1  = (const float*)d_in[13];
    const float* be1 = (const float*)d_in[14];
    const float* g2  = (const float*)d_in[15];
    const float* be2 = (const float*)d_in[16];

    char* ws = (char*)d_ws;
    unsigned short* wt  = (unsigned short*)ws;                       // 200KB of WT planes
    unsigned short* xT0 = (unsigned short*)(ws + ((size_t)1 << 20));
    unsigned short* xR0 = (unsigned short*)(ws + ((size_t)2 << 20));
    unsigned short* xTa = (unsigned short*)(ws + ((size_t)4 << 20));  // 8MB
    unsigned short* xRa = (unsigned short*)(ws + ((size_t)12 << 20));
    unsigned short* xTb = (unsigned short*)(ws + ((size_t)20 << 20));
    unsigned short* xRb = (unsigned short*)(ws + ((size_t)28 << 20));
    float* part = (float*)(ws + ((size_t)36 << 20));

    unsigned short* WT0h = wt;
    unsigned short* WT0l = wt + 2048;
    unsigned short* WT1h = wt + 4096;
    unsigned short* WT1l = wt + 20480;
    unsigned short* WT2h = wt + 36864;
    unsigned short* WT2l = wt + 53248;
    unsigned short* WT3h = wt + 69632;
    unsigned short* WT3l = wt + 86016;

    wconv<<<dim3(200), 256, 0, stream>>>(W0, W1, W2, W3, wt);
    x0conv<<<dim3(128), 256, 0, stream>>>(x, xT0, xR0);

    dim3 grid(16, 32);
    gcn_block<0><<<grid, 256, 0, stream>>>(xT0, xR0, co, psq, WT0h, WT0l, g0, be0, b0, xTa, xRa, nullptr);
    gcn_block<1><<<grid, 256, 0, stream>>>(xTa, xRa, co, psq, WT1h, WT1l, g1, be1, b1, xTb, xRb, nullptr);
    gcn_block<1><<<grid, 256, 0, stream>>>(xTb, xRb, co, psq, WT2h, WT2l, g2, be2, b2, xTa, xRa, nullptr);
    gcn_block<2><<<grid, 256, 0, stream>>>(xTa, xRa, co, psq, WT3h, WT3l, nullptr, nullptr, nullptr,
                                           nullptr, nullptr, part);
    finalize_kernel<<<1, 64, 0, stream>>>(part, b3, (float*)d_out);
}

// Round 3
// 204.284 us; speedup vs baseline: 10.8152x; 1.3211x over previous
//
#include <hip/hip_runtime.h>
#include <math.h>

typedef __attribute__((ext_vector_type(8)))  __bf16   bf16x8;
typedef __attribute__((ext_vector_type(4)))  float    f32x4;
typedef __attribute__((ext_vector_type(16))) float    f32x16;
typedef __attribute__((ext_vector_type(4)))  unsigned u32x4;
typedef __attribute__((ext_vector_type(2)))  unsigned u32x2;

__device__ __forceinline__ unsigned short f2bf(float f) {
    unsigned u = __builtin_bit_cast(unsigned, f);
    u += 0x7fffu + ((u >> 16) & 1u);
    return (unsigned short)(u >> 16);
}
__device__ __forceinline__ float bf2f(unsigned short b) {
    unsigned u = ((unsigned)b) << 16;
    return __builtin_bit_cast(float, u);
}
__device__ __forceinline__ unsigned swz3(int key) { return (unsigned)((key ^ (key >> 3)) & 7); }
__device__ __forceinline__ bf16x8 ldfrag(const char* p) { return __builtin_bit_cast(bf16x8, *(const u32x4*)p); }

// ---------------------------------------------------------------------------
// W transpose -> bf16 (hi only).  Layout in wt (elements):
// [0] WT0[64][32]  [2048] WT1[64][256]  [18432] WT2[64][256]
// [34816] WT3[64][256] (rows 4..63 zero)
__global__ __launch_bounds__(256)
void wconv(const float* __restrict__ W0, const float* __restrict__ W1,
           const float* __restrict__ W2, const float* __restrict__ W3,
           unsigned short* __restrict__ wt)
{
    int id = blockIdx.x * 256 + threadIdx.x;
    if (id >= 51200) return;
    float v; size_t dst;
    if (id < 2048)       { int h = id >> 5, f = id & 31;              v = W0[f*64 + h]; dst = (size_t)h*32 + f; }
    else if (id < 18432) { int j = id - 2048;  int h = j >> 8, f = j & 255; v = W1[f*64 + h]; dst = 2048  + (size_t)h*256 + f; }
    else if (id < 34816) { int j = id - 18432; int h = j >> 8, f = j & 255; v = W2[f*64 + h]; dst = 18432 + (size_t)h*256 + f; }
    else                 { int j = id - 34816; int h = j >> 8, f = j & 255; v = (h < 4) ? W3[f*4 + h] : 0.f; dst = 34816 + (size_t)h*256 + f; }
    wt[dst] = f2bf(v);
}

// x fp32 [32][1024][16] -> xT0 bf16 [32][16][1024] + xR0 bf16 [32][1024][16]
__global__ __launch_bounds__(256)
void x0conv(const float* __restrict__ x, unsigned short* __restrict__ xT0,
            unsigned short* __restrict__ xR0)
{
    int id = blockIdx.x * 256 + threadIdx.x;   // 32768 = 32*1024
    int b = id >> 10, j = id & 1023;
    const float* s = x + (size_t)id * 16;
    unsigned pk[8];
#pragma unroll
    for (int f = 0; f < 16; f += 2) {
        unsigned short h0 = f2bf(s[f]);
        unsigned short h1 = f2bf(s[f + 1]);
        xT0[((size_t)b*16 + f    )*1024 + j] = h0;
        xT0[((size_t)b*16 + f + 1)*1024 + j] = h1;
        pk[f >> 1] = (unsigned)h0 | ((unsigned)h1 << 16);
    }
    u32x4* d = (u32x4*)(xR0 + (size_t)id * 16);
    u32x4 v0 = {pk[0], pk[1], pk[2], pk[3]};
    u32x4 v1 = {pk[4], pk[5], pk[6], pk[7]};
    d[0] = v0; d[1] = v1;
}

// ---------------------------------------------------------------------------
// MODE 0: F=16 first block — generates T (bf16, rounded), writes T + Rinv to
// global, consumes T itself.  MODE 1: F=128 mid — stages T from global.
// MODE 2: F=128 final — like 1 but partial-mean epilogue.
template<int MODE>
__global__ __launch_bounds__(256, 2)
void gcn_block(const unsigned short* __restrict__ xT, const unsigned short* __restrict__ xR,
               const float* __restrict__ coords, const float* __restrict__ psq,
               const unsigned short* __restrict__ WThi,
               const float* __restrict__ gamma, const float* __restrict__ beta,
               const float* __restrict__ bias,
               unsigned short* __restrict__ Tg, float* __restrict__ RinvG,
               unsigned short* __restrict__ oxT, unsigned short* __restrict__ oxR,
               float* __restrict__ part)
{
    __shared__ char smem[65536];
    // MODE0 layout
    constexpr int XTO = 0;            // x^T tile [16][128B]
    constexpr int THI = 16 * 1024;    // T tile [64][128B] swizzled
    constexpr int SC4 = 32 * 1024;    // coords float4[1024]
    constexpr int C0O = 0;            // concat [64][64B]
    constexpr int W0H = 4 * 1024;     // W0T [64][64B]
    constexpr int RED = SC4;
    constexpr int RIV = SC4 + 1024;
    // MODE1/2 layout
    constexpr int XTB  = 0;           // x^T dbuf [2][128][128B]
    constexpr int TTB  = 32 * 1024;   // T dbuf [2][64][128B]
    constexpr int RIVM = 48 * 1024;
    constexpr int YL   = 0;           // dense: y [64][256B]
    constexpr int XI   = 16 * 1024;   // dense: xi [64][256B]
    constexpr int WTB  = 32 * 1024;   // dense: WT [64][256B]
    constexpr int SPT  = 48 * 1024 + 512;
    constexpr int ZT   = 0;           // z fp32 [64][65]

    const int t = threadIdx.x;
    const int l = t & 63;
    const int w = t >> 6;
    const int b  = blockIdx.y;
    const int it = blockIdx.x;
    const int i0g = it * 64;
    const int m31 = l & 31, kg = l >> 5;
    const int m15 = l & 15, kg4 = l >> 4;
    const int wf = w >> 1, wi = w & 1;
    float bv = 0.f;
    if constexpr (MODE != 2) bv = bias[0];

    int fA0 = 0, fA1 = 0, iB = 0;
    if constexpr (MODE) { fA0 = wf*64 + m31; fA1 = fA0 + 32; iB = wi*32 + m31; }
    else                { fA0 = m15;                          iB = w*16 + m15; }

    f32x16 acc0, acc1; f32x4 acc4;
#pragma unroll
    for (int r = 0; r < 16; ++r) { acc0[r] = 0.f; acc1[r] = 0.f; }
#pragma unroll
    for (int r = 0; r < 4; ++r) acc4[r] = 0.f;

    if constexpr (MODE == 0) {
        const float p = psq[0];
        float4* sc = (float4*)(smem + SC4);
        for (int k = t; k < 1024; k += 256) {
            const float* c = coords + ((size_t)b * 1024 + k) * 3;
            float cx = c[0], cy = c[1], cz = c[2];
            sc[k] = make_float4(cx, cy, cz, cx*cx + cy*cy + cz*cz);
        }
        __syncthreads();
        const float4 ci = sc[i0g + l];
        float rsum = 0.f;

        for (int jt = 0; jt < 16; ++jt) {
            __syncthreads();
            if (t < 128) {
                const int f = t >> 3, g8 = t & 7;
                const unsigned short* g = xT + ((size_t)b*16 + f)*1024 + jt*64 + g8*8;
                u32x4 v = *(const u32x4*)g;
                *(u32x4*)(smem + XTO + f*128 + ((g8*16) ^ (swz3(f) << 4))) = v;
            }
            {   // T-gen: thread (i=l, jgroup=w), 16 j each; rsum from ROUNDED vals
                const int j0 = jt*64 + w*16;
                unsigned hp[8];
#pragma unroll
                for (int q = 0; q < 8; ++q) {
                    float4 cj0 = sc[j0 + 2*q], cj1 = sc[j0 + 2*q + 1];
                    float d0 = ci.w + cj0.w - 2.f*(ci.x*cj0.x + ci.y*cj0.y + ci.z*cj0.z);
                    float d1 = ci.w + cj1.w - 2.f*(ci.x*cj1.x + ci.y*cj1.y + ci.z*cj1.z);
                    unsigned short h0 = f2bf(__expf(__expf(-d0 * p)));
                    unsigned short h1 = f2bf(__expf(__expf(-d1 * p)));
                    rsum += bf2f(h0) + bf2f(h1);
                    hp[q] = (unsigned)h0 | ((unsigned)h1 << 16);
                }
                const unsigned sw = swz3(l) << 4;
                char* th = smem + THI + l*128;
                u32x4 a = {hp[0], hp[1], hp[2], hp[3]}, c2 = {hp[4], hp[5], hp[6], hp[7]};
                *(u32x4*)(th + ((w*32 +  0) ^ sw)) = a;
                *(u32x4*)(th + ((w*32 + 16) ^ sw)) = c2;
            }
            __syncthreads();
            {   // write T tile to global (coalesced via LDS)
                const int r = t >> 2, c = t & 3;
                const char* th = smem + THI + r*128;
                const unsigned swr = swz3(r) << 4;
                u32x4 v0 = *(const u32x4*)(th + ((c*32     ) ^ swr));
                u32x4 v1 = *(const u32x4*)(th + ((c*32 + 16) ^ swr));
                unsigned short* dT = Tg + ((size_t)(b*1024 + i0g + r))*1024 + jt*64 + c*16;
                *(u32x4*)dT = v0;
                *(u32x4*)(dT + 8) = v1;
            }
            {   // MFMA
                const char* rA  = smem + XTO + fA0*128; const unsigned sA = swz3(fA0) << 4;
                const char* rBh = smem + THI + iB*128;  const unsigned sB = swz3(iB) << 4;
#pragma unroll
                for (int kk = 0; kk < 2; ++kk) {
                    const unsigned off = kk*64 + kg4*16;
                    bf16x8 a  = ldfrag(rA  + (off ^ sA));
                    bf16x8 bh = ldfrag(rBh + (off ^ sB));
                    acc4 = __builtin_amdgcn_mfma_f32_16x16x32_bf16(a, bh, acc4, 0, 0, 0);
                }
            }
        }
        // rowsum reduce -> Rinv (LDS + global)
        __syncthreads();
        ((float*)(smem + RED))[w*64 + l] = rsum;
        __syncthreads();
        if (t < 64) {
            const float* rr = (const float*)(smem + RED);
            float s = rr[t] + rr[64 + t] + rr[128 + t] + rr[192 + t];
            float rv = 1.f / s;
            ((float*)(smem + RIV))[t] = rv;
            RinvG[(size_t)b*1024 + i0g + t] = rv;
        }
        __syncthreads();
    } else {
        // ---- MODE 1/2: T from global, double-buffered reg staging ----
        if (t < 64) ((float*)(smem + RIVM))[t] = RinvG[(size_t)b*1024 + i0g + t];
        const int sf = t >> 1, shf = t & 1;
        const int sti = t >> 2, stc = t & 3;
        const unsigned short* gxb = xT + ((size_t)b*128 + sf)*1024 + shf*32;
        const unsigned short* gtb = Tg + ((size_t)(b*1024 + i0g + sti))*1024 + stc*16;
        u32x4 rx0, rx1, rx2, rx3, rt0, rt1;
        rx0 = *(const u32x4*)(gxb);      rx1 = *(const u32x4*)(gxb + 8);
        rx2 = *(const u32x4*)(gxb + 16); rx3 = *(const u32x4*)(gxb + 24);
        rt0 = *(const u32x4*)(gtb);      rt1 = *(const u32x4*)(gtb + 8);

        const unsigned swx = swz3(sf) << 4;
        const unsigned swt = swz3(sti) << 4;
        const unsigned sA0 = swz3(fA0) << 4;
        const unsigned sA1 = swz3(fA1) << 4;
        const unsigned sB  = swz3(iB) << 4;

        for (int jt = 0; jt < 16; ++jt) {
            const int p = jt & 1;
            {   // ds_write staged tile
                char* xrow = smem + XTB + p*16384 + sf*128;
                *(u32x4*)(xrow + ((shf*64 +  0) ^ swx)) = rx0;
                *(u32x4*)(xrow + ((shf*64 + 16) ^ swx)) = rx1;
                *(u32x4*)(xrow + ((shf*64 + 32) ^ swx)) = rx2;
                *(u32x4*)(xrow + ((shf*64 + 48) ^ swx)) = rx3;
                char* trow = smem + TTB + p*8192 + sti*128;
                *(u32x4*)(trow + ((stc*32     ) ^ swt)) = rt0;
                *(u32x4*)(trow + ((stc*32 + 16) ^ swt)) = rt1;
            }
            if (jt < 15) {   // issue next tile loads (overlap with MFMA below)
                const unsigned short* g = gxb + (jt + 1)*64;
                rx0 = *(const u32x4*)(g);      rx1 = *(const u32x4*)(g + 8);
                rx2 = *(const u32x4*)(g + 16); rx3 = *(const u32x4*)(g + 24);
                const unsigned short* gT = gtb + (jt + 1)*64;
                rt0 = *(const u32x4*)(gT);     rt1 = *(const u32x4*)(gT + 8);
            }
            __syncthreads();
            const char* rA0 = smem + XTB + p*16384 + fA0*128;
            const char* rA1 = smem + XTB + p*16384 + fA1*128;
            const char* rBh = smem + TTB + p*8192  + iB*128;
#pragma unroll
            for (int kk = 0; kk < 4; ++kk) {
                const unsigned off = kk*32 + kg*16;
                bf16x8 a0 = ldfrag(rA0 + (off ^ sA0));
                bf16x8 a1 = ldfrag(rA1 + (off ^ sA1));
                bf16x8 bh = ldfrag(rBh + (off ^ sB));
                acc0 = __builtin_amdgcn_mfma_f32_32x32x16_bf16(a0, bh, acc0, 0, 0, 0);
                acc1 = __builtin_amdgcn_mfma_f32_32x32x16_bf16(a1, bh, acc1, 0, 0, 0);
            }
        }
        __syncthreads();   // main loop fully done; LDS is repurposed below
    }

    // ---- normalize y -> concat buffers; stage xi ----
    if constexpr (MODE) {
        const float rv = ((const float*)(smem + RIVM))[iB];
        acc0 *= rv; acc1 *= rv;
        char* yrow = smem + YL + iB*256;
        const unsigned swi = swz3(iB) << 4;
#pragma unroll
        for (int rq = 0; rq < 4; ++rq) {
            unsigned q0 = (unsigned)f2bf(acc0[rq*4+0]) | ((unsigned)f2bf(acc0[rq*4+1]) << 16);
            unsigned q1 = (unsigned)f2bf(acc0[rq*4+2]) | ((unsigned)f2bf(acc0[rq*4+3]) << 16);
            u32x2 w0 = {q0, q1};
            *(u32x2*)(yrow + ((wf*128 + rq*16 + kg*8) ^ swi)) = w0;
            unsigned r0 = (unsigned)f2bf(acc1[rq*4+0]) | ((unsigned)f2bf(acc1[rq*4+1]) << 16);
            unsigned r1 = (unsigned)f2bf(acc1[rq*4+2]) | ((unsigned)f2bf(acc1[rq*4+3]) << 16);
            u32x2 w1 = {r0, r1};
            *(u32x2*)(yrow + ((wf*128 + 64 + rq*16 + kg*8) ^ swi)) = w1;
        }
        const int xi_i = t >> 2, xq = t & 3;
        const unsigned short* gx = xR + ((size_t)(b*1024 + i0g + xi_i))*128 + xq*32;
        char* xrow = smem + XI + xi_i*256;
        const unsigned swxi = swz3(xi_i) << 4;
#pragma unroll
        for (int g = 0; g < 4; ++g) {
            u32x4 v = *(const u32x4*)(gx + g*8);
            *(u32x4*)(xrow + ((xq*64 + g*16) ^ swxi)) = v;
        }
        // stage WT part A (f 0..127)
        {
            const int h = t >> 2, q = t & 3;
            const unsigned short* gw = WThi + h*256 + q*32;
            char* wrow = smem + WTB + h*256;
            const unsigned sw = swz3(h) << 4;
#pragma unroll
            for (int g = 0; g < 4; ++g) {
                u32x4 v = *(const u32x4*)(gw + g*8);
                *(u32x4*)(wrow + ((q*64 + g*16) ^ sw)) = v;
            }
        }
    } else {
        const float rv = ((const float*)(smem + RIV))[iB];
        acc4 *= rv;
        unsigned q0 = (unsigned)f2bf(acc4[0]) | ((unsigned)f2bf(acc4[1]) << 16);
        unsigned q1 = (unsigned)f2bf(acc4[2]) | ((unsigned)f2bf(acc4[3]) << 16);
        u32x2 w0 = {q0, q1};
        *(u32x2*)(smem + C0O + iB*64 + ((kg4*8) ^ ((swz3(iB) & 3) << 4))) = w0;
        const int xi_i = t >> 2, xq = t & 3;
        const unsigned short* gx = xR + ((size_t)(b*1024 + i0g + xi_i))*16 + xq*4;
        u32x2 v = *(const u32x2*)gx;
        *(u32x2*)(smem + C0O + xi_i*64 + ((32 + xq*8) ^ ((swz3(xi_i) & 3) << 4))) = v;
    }
    __syncthreads();

    // ---- dense: z^T = WT @ concat^T ----
    f32x16 dacc; f32x4 da0, da1, da2, da3;
#pragma unroll
    for (int r = 0; r < 16; ++r) dacc[r] = bv;
#pragma unroll
    for (int r = 0; r < 4; ++r) { da0[r] = bv; da1[r] = bv; da2[r] = bv; da3[r] = bv; }

    if constexpr (MODE) {
        const int hA = wf*32 + m31;
        const char* rWh = smem + WTB + hA*256;  const unsigned sH = swz3(hA) << 4;
        const char* rBY = smem + YL + iB*256;   const unsigned sI = swz3(iB) << 4;
#pragma unroll
        for (int k8 = 0; k8 < 8; ++k8) {
            const unsigned off = k8*32 + kg*16;
            bf16x8 ah = ldfrag(rWh + (off ^ sH));
            bf16x8 bb = ldfrag(rBY + (off ^ sI));
            dacc = __builtin_amdgcn_mfma_f32_32x32x16_bf16(ah, bb, dacc, 0, 0, 0);
        }
        __syncthreads();
        {   // stage WT part B (f 128..255)
            const int h = t >> 2, q = t & 3;
            const unsigned short* gw = WThi + h*256 + 128 + q*32;
            char* wrow = smem + WTB + h*256;
            const unsigned sw = swz3(h) << 4;
#pragma unroll
            for (int g = 0; g < 4; ++g) {
                u32x4 v = *(const u32x4*)(gw + g*8);
                *(u32x4*)(wrow + ((q*64 + g*16) ^ sw)) = v;
            }
        }
        __syncthreads();
        const char* rBX = smem + XI + iB*256;
#pragma unroll
        for (int k8 = 0; k8 < 8; ++k8) {
            const unsigned off = k8*32 + kg*16;
            bf16x8 ah = ldfrag(rWh + (off ^ sH));
            bf16x8 bb = ldfrag(rBX + (off ^ sI));
            dacc = __builtin_amdgcn_mfma_f32_32x32x16_bf16(ah, bb, dacc, 0, 0, 0);
        }
        __syncthreads();
    } else {
        {   // stage W0T
            if (t < 128) {
                const int h = t >> 1, hf = t & 1;
                const unsigned short* gw = WThi + h*32 + hf*16;
                char* wrow = smem + W0H + h*64;
                const unsigned sw2 = (swz3(h) & 3) << 4;
#pragma unroll
                for (int g = 0; g < 2; ++g) {
                    u32x4 v = *(const u32x4*)(gw + g*8);
                    *(u32x4*)(wrow + (((hf*2 + g)*16) ^ sw2)) = v;
                }
            }
        }
        __syncthreads();
        const int hA = w*16 + m15;
        const unsigned sH2 = (swz3(hA) & 3) << 4;
        bf16x8 ah = ldfrag(smem + W0H + hA*64 + ((kg4*16) ^ sH2));
        {
            const int i0 = m15;
            bf16x8 b0 = ldfrag(smem + C0O + (i0     )*64 + ((kg4*16) ^ ((swz3(i0     ) & 3) << 4)));
            bf16x8 b1 = ldfrag(smem + C0O + (i0 + 16)*64 + ((kg4*16) ^ ((swz3(i0 + 16) & 3) << 4)));
            bf16x8 b2 = ldfrag(smem + C0O + (i0 + 32)*64 + ((kg4*16) ^ ((swz3(i0 + 32) & 3) << 4)));
            bf16x8 b3 = ldfrag(smem + C0O + (i0 + 48)*64 + ((kg4*16) ^ ((swz3(i0 + 48) & 3) << 4)));
            da0 = __builtin_amdgcn_mfma_f32_16x16x32_bf16(ah, b0, da0, 0, 0, 0);
            da1 = __builtin_amdgcn_mfma_f32_16x16x32_bf16(ah, b1, da1, 0, 0, 0);
            da2 = __builtin_amdgcn_mfma_f32_16x16x32_bf16(ah, b2, da2, 0, 0, 0);
            da3 = __builtin_amdgcn_mfma_f32_16x16x32_bf16(ah, b3, da3, 0, 0, 0);
        }
        __syncthreads();
    }

    // ---- epilogue ----
    float* zt = (float*)(smem + ZT);
    if constexpr (MODE == 2) {
        if (wf == 0) {
#pragma unroll
            for (int r = 0; r < 4; ++r) {
                float v = dacc[r];
                v += __shfl_xor(v, 1);  v += __shfl_xor(v, 2);  v += __shfl_xor(v, 4);
                v += __shfl_xor(v, 8);  v += __shfl_xor(v, 16);
                if (l == 0) ((float*)(smem + SPT))[w*4 + r] = v;
            }
        }
        __syncthreads();
        if (t < 4) {
            const float* sp = (const float*)(smem + SPT);
            part[((size_t)b*16 + it)*4 + t] = sp[t] + sp[4 + t];
        }
        return;
    } else {
        const float bns = rsqrtf(1.f + 1e-3f);
        if constexpr (MODE) {
#pragma unroll
            for (int r = 0; r < 16; ++r) {
                const int h = wf*32 + (r & 3) + 8*(r >> 2) + 4*kg;
                zt[h*65 + iB] = dacc[r] * (gamma[h] * bns) + beta[h];
            }
        } else {
#pragma unroll
            for (int r = 0; r < 4; ++r) {
                const int h = w*16 + kg4*4 + r;
                const float gs = gamma[h] * bns, bt = beta[h];
                zt[h*65 + (m15     )] = da0[r] * gs + bt;
                zt[h*65 + (m15 + 16)] = da1[r] * gs + bt;
                zt[h*65 + (m15 + 32)] = da2[r] * gs + bt;
                zt[h*65 + (m15 + 48)] = da3[r] * gs + bt;
            }
        }
        __syncthreads();
        // emit next-layer planes: xT' [128][1024], xR' [1024][128]
        {
            const int h = t & 63, ic = (t >> 6) * 16;
            const float* zr = zt + h*65 + ic;
            unsigned pz[8], pr[8];
#pragma unroll
            for (int q = 0; q < 8; ++q) {
                float z0 = zr[2*q], z1 = zr[2*q + 1];
                pz[q] = (unsigned)f2bf(z0) | ((unsigned)f2bf(z1) << 16);
                pr[q] = (unsigned)f2bf(fmaxf(z0, 0.f)) | ((unsigned)f2bf(fmaxf(z1, 0.f)) << 16);
            }
            unsigned short* d0 = oxT + ((size_t)b*128 + h     )*1024 + i0g + ic;
            unsigned short* d1 = oxT + ((size_t)b*128 + h + 64)*1024 + i0g + ic;
            u32x4 a = {pz[0], pz[1], pz[2], pz[3]}, c = {pz[4], pz[5], pz[6], pz[7]};
            u32x4 e = {pr[0], pr[1], pr[2], pr[3]}, f = {pr[4], pr[5], pr[6], pr[7]};
            *(u32x4*)(d0) = a; *(u32x4*)(d0 + 8) = c;
            *(u32x4*)(d1) = e; *(u32x4*)(d1 + 8) = f;
        }
        {
            const int i = t >> 2, fq = t & 3;
            unsigned pk[16];
#pragma unroll
            for (int ff = 0; ff < 16; ++ff) {
                const int f0 = fq*32 + ff*2, f1 = f0 + 1;
                float v0 = (f0 < 64) ? zt[f0*65 + i] : fmaxf(zt[(f0 - 64)*65 + i], 0.f);
                float v1 = (f1 < 64) ? zt[f1*65 + i] : fmaxf(zt[(f1 - 64)*65 + i], 0.f);
                pk[ff] = (unsigned)f2bf(v0) | ((unsigned)f2bf(v1) << 16);
            }
            unsigned short* d = oxR + ((size_t)(b*1024 + i0g + i))*128 + fq*32;
            u32x4 a = {pk[0],  pk[1],  pk[2],  pk[3]};
            u32x4 c = {pk[4],  pk[5],  pk[6],  pk[7]};
            u32x4 e = {pk[8],  pk[9],  pk[10], pk[11]};
            u32x4 f = {pk[12], pk[13], pk[14], pk[15]};
            *(u32x4*)(d)      = a; *(u32x4*)(d + 8)  = c;
            *(u32x4*)(d + 16) = e; *(u32x4*)(d + 24) = f;
        }
    }
}

__global__ void finalize_kernel(const float* __restrict__ part, const float* __restrict__ b3,
                                float* __restrict__ out)
{
    const int b = threadIdx.x;
    if (b < 32) {
        float v[4] = {0.f, 0.f, 0.f, 0.f};
        for (int i = 0; i < 16; ++i)
#pragma unroll
            for (int h = 0; h < 4; ++h) v[h] += part[((size_t)b*16 + i)*4 + h];
        const float bb = b3[0];
#pragma unroll
        for (int h = 0; h < 4; ++h) v[h] = v[h] * (1.f / 1024.f) + bb;
        const float m = fmaxf(fmaxf(v[0], v[1]), fmaxf(v[2], v[3]));
        float e[4], se = 0.f;
#pragma unroll
        for (int h = 0; h < 4; ++h) { e[h] = __expf(v[h] - m); se += e[h]; }
        const float inv = 1.f / se;
#pragma unroll
        for (int h = 0; h < 4; ++h) out[b*4 + h] = e[h] * inv;
    }
}

extern "C" void kernel_launch(void* const* d_in, const int* in_sizes, int n_in,
                              void* d_out, int out_size, void* d_ws, size_t ws_size,
                              hipStream_t stream)
{
    const float* x   = (const float*)d_in[0];
    const float* co  = (const float*)d_in[1];
    const float* psq = (const float*)d_in[2];
    const float* W0  = (const float*)d_in[3];
    const float* W1  = (const float*)d_in[4];
    const float* W2  = (const float*)d_in[5];
    const float* W3  = (const float*)d_in[6];
    const float* b0  = (const float*)d_in[7];
    const float* b1  = (const float*)d_in[8];
    const float* b2  = (const float*)d_in[9];
    const float* b3  = (const float*)d_in[10];
    const float* g0  = (const float*)d_in[11];
    const float* be0 = (const float*)d_in[12];
    const float* g1  = (const float*)d_in[13];
    const float* be1 = (const float*)d_in[14];
    const float* g2  = (const float*)d_in[15];
    const float* be2 = (const float*)d_in[16];

    char* ws = (char*)d_ws;
    const size_t MB = (size_t)1 << 20;
    unsigned short* Tg  = (unsigned short*)(ws);             // 64 MB
    unsigned short* xTa = (unsigned short*)(ws + 64*MB);     // 8 MB
    unsigned short* xRa = (unsigned short*)(ws + 72*MB);
    unsigned short* xTb = (unsigned short*)(ws + 80*MB);
    unsigned short* xRb = (unsigned short*)(ws + 88*MB);
    unsigned short* xT0 = (unsigned short*)(ws + 96*MB);     // 1 MB
    unsigned short* xR0 = (unsigned short*)(ws + 97*MB);     // 1 MB
    unsigned short* wt  = (unsigned short*)(ws + 98*MB);     // 100 KB
    float* RinvG        = (float*)(ws + 98*MB + 256*1024);   // 128 KB
    float* part         = (float*)(ws + 98*MB + 512*1024);   // 8 KB

    unsigned short* WT0 = wt;
    unsigned short* WT1 = wt + 2048;
    unsigned short* WT2 = wt + 18432;
    unsigned short* WT3 = wt + 34816;

    wconv<<<dim3(200), 256, 0, stream>>>(W0, W1, W2, W3, wt);
    x0conv<<<dim3(128), 256, 0, stream>>>(x, xT0, xR0);

    dim3 grid(16, 32);
    gcn_block<0><<<grid, 256, 0, stream>>>(xT0, xR0, co, psq, WT0, g0, be0, b0, Tg, RinvG, xTa, xRa, nullptr);
    gcn_block<1><<<grid, 256, 0, stream>>>(xTa, xRa, nullptr, nullptr, WT1, g1, be1, b1, Tg, RinvG, xTb, xRb, nullptr);
    gcn_block<1><<<grid, 256, 0, stream>>>(xTb, xRb, nullptr, nullptr, WT2, g2, be2, b2, Tg, RinvG, xTa, xRa, nullptr);
    gcn_block<2><<<grid, 256, 0, stream>>>(xTa, xRa, nullptr, nullptr, WT3, nullptr, nullptr, nullptr, Tg, RinvG,
                                           nullptr, nullptr, part);
    finalize_kernel<<<1, 64, 0, stream>>>(part, b3, (float*)d_out);
}